// Round 9
// baseline (320.239 us; speedup 1.0000x reference)
//
#include <hip/hip_runtime.h>
#include <hip/hip_cooperative_groups.h>
#include <cstdint>

namespace cg = cooperative_groups;

#define NCLS 3
#define NPTS 100000
#define NB 2
#define PRE 512
#define POST 100
#define SCORE_TH 0.1f
#define NMS_TH 0.25
#define CAP 1024            // candidate buffer per problem (expect ~690)
#define BPP 98              // 1024-point chunks per plane (98*1024 >= 100000)
#define NBINS 384           // fast-key bins: (key>>17) - (0xBD000000>>17)
#define BIN_SH 17
#define BIN_OFFW (0xBD000000u >> BIN_SH)
#define FMARG 2e-5f         // 2x bound on |f32 sigmoid - f64 sigmoid| (<=1e-6)
#define NPROB (NB * NCLS)
#define WAVES_PER_PROB 2304  // 36 upper-tri 64x64 cells x 64 rows
#define HPB (NCLS * NBINS)   // 1152 partial-hist entries per hist segment
#define GRID 256             // 1 block/CU -> cooperative co-residency trivial
#define BLK 256

// ---------------- ws layout (bytes) ---------------- (NO memset needed)
// pivots    : uint32 [6] (pad 64)   @ 0           (written P2)
// cand_cnt  : uint32 [6] (pad 64)   @ 64          (zeroed P2)
// mask      : uint64 [6*PRE*8]      @ 128         (196,608; upper-tri words
//                                                  always stored by P5;
//                                                  lower-tri garbage harmless)
// cand      : uint64 [6*CAP]        @ 196,736     (49,152)
// cand_idx  : uint32 [6*PRE]        @ 245,888     (12,288)
// cand_scr  : float  [6*PRE]        @ 258,176     (12,288)
// boxdata   : double [6*PRE*20]     @ 270,464     (491,520)
// screen    : float  [6*PRE*8]      @ 761,984     (98,304)
// sf        : float  [6*NPTS]       @ 860,288     (2,400,000)  plane-major
// hist_part : uint32 [196*1152]     @ 3,260,288   (903,168)
// total ~4.16 MB

#define OFF_PIVOTS    0
#define OFF_CANDCNT   64
#define OFF_MASK      128
#define OFF_CAND      196736
#define OFF_CANDIDX   245888
#define OFF_CANDSCR   258176
#define OFF_BOXDATA   270464
#define OFF_SCREEN    761984
#define OFF_SF        860288
#define OFF_HISTPART  3260288

__device__ __forceinline__ uint32_t score_key(float x)
{
    // EXACT path: f64 sigmoid rounded to f32 == reference (absmax 0.0 R1-R8)
    double sd = 1.0 / (1.0 + exp(-(double)x));
    float s = (float)sd;
    if (!(s >= SCORE_TH)) s = -1.0f;
    uint32_t u = __float_as_uint(s);
    return (u & 0x80000000u) ? ~u : (u | 0x80000000u);
}

__device__ __forceinline__ float fast_sig(float x)
{
    return 1.0f / (1.0f + __expf(-x));
}

// monotone bin of a (possibly margin-adjusted) f32 score
__device__ __forceinline__ int fast_bin(float s)
{
    float v = (s >= SCORE_TH) ? s : -1.0f;
    uint32_t u = __float_as_uint(v);
    uint32_t kk = (u & 0x80000000u) ? ~u : (u | 0x80000000u);
    int b = (int)(kk >> BIN_SH) - (int)BIN_OFFW;
    return b < 0 ? 0 : (b > NBINS - 1 ? NBINS - 1 : b);
}

// Single cooperative kernel: 6 dispatches -> 1. Phase bodies are the
// verified R8 kernels verbatim; grid.sync() replaces launch boundaries
// (and provides the same device-scope visibility).
__global__ __launch_bounds__(BLK) void fused_kernel(
    const float* __restrict__ cls, const float* __restrict__ boxes,
    float* __restrict__ out, char* __restrict__ ws)
{
    uint32_t* pivots      = (uint32_t*)(ws + OFF_PIVOTS);
    uint32_t* cand_cnt    = (uint32_t*)(ws + OFF_CANDCNT);
    unsigned long long* mask = (unsigned long long*)(ws + OFF_MASK);
    unsigned long long* cand = (unsigned long long*)(ws + OFF_CAND);
    uint32_t* cand_idx    = (uint32_t*)(ws + OFF_CANDIDX);
    float*    cand_score  = (float*)   (ws + OFF_CANDSCR);
    double*   boxdata     = (double*)  (ws + OFF_BOXDATA);
    float*    screen      = (float*)   (ws + OFF_SCREEN);
    float*    sf          = (float*)   (ws + OFF_SF);
    uint32_t* hist_part   = (uint32_t*)(ws + OFF_HISTPART);

    __shared__ uint32_t sh_hist[HPB];                 // P1 hist / P2 bins+csum
    __shared__ unsigned long long sh_key[CAP];        // P3 stage / P4 sort keys
    __shared__ uint32_t sh_lcnt, sh_lbase;
    __shared__ unsigned long long sh_smask[PRE * 8];  // P6 (32 KB)
    __shared__ float sh_sscore[PRE];
    __shared__ int sh_slist[POST];
    __shared__ int sh_scnt;

    cg::grid_group grid = cg::this_grid();
    const int tid = threadIdx.x;

    // ---- P1: fast sigmoid + per-segment partial histograms ----
    {
        const int seg = blockIdx.x;
        if (seg < NB * BPP) {
            for (int t = tid; t < HPB; t += BLK) sh_hist[t] = 0;
            __syncthreads();
            const int b = seg / BPP, cb = seg % BPP;
            #pragma unroll
            for (int it = 0; it < 4; ++it) {
                int i = cb * 1024 + it * BLK + tid;
                if (i < NPTS) {
                    const float* cp = cls + ((size_t)b * NPTS + i) * NCLS;
                    #pragma unroll
                    for (int k = 0; k < NCLS; ++k) {
                        float sfv = fast_sig(cp[k]);
                        sf[(size_t)(b * NCLS + k) * NPTS + i] = sfv;
                        atomicAdd(&sh_hist[k * NBINS + fast_bin(sfv)], 1u);
                    }
                }
            }
            __syncthreads();
            uint32_t* P = hist_part + (size_t)seg * HPB;
            for (int t = tid; t < HPB; t += BLK) P[t] = sh_hist[t];
        }
    }
    grid.sync();

    // ---- P2: reduce partials -> pivot bin; zero cand_cnt ----
    if (blockIdx.x < NPROB) {
        const int p = blockIdx.x, b = p / NCLS, k = p % NCLS;
        uint32_t* bins = sh_hist;            // 384
        uint32_t* csum = sh_hist + NBINS;    // 128
        for (int bin = tid; bin < NBINS; bin += BLK) {
            uint32_t s = 0;
            const uint32_t* base =
                hist_part + (size_t)(b * BPP) * HPB + k * NBINS + bin;
            for (int c = 0; c < BPP; ++c) s += base[(size_t)c * HPB];
            bins[bin] = s;
        }
        __syncthreads();
        if (tid < 128)
            csum[tid] = bins[tid * 3] + bins[tid * 3 + 1] + bins[tid * 3 + 2];
        __syncthreads();
        if (tid == 0) {
            int cum = 0, cchunk = 0;
            for (int c = 127; c >= 0; --c) {
                if (cum + (int)csum[c] >= PRE) { cchunk = c; break; }
                cum += (int)csum[c];
            }
            uint32_t pb = 0;
            for (int bin = cchunk * 3 + 2; bin >= cchunk * 3; --bin) {
                int h = (int)bins[bin];
                if (cum + h >= PRE) { pb = (uint32_t)bin; break; }
                cum += h;
            }
            pivots[p] = pb;
            cand_cnt[p] = 0;
        }
    }
    grid.sync();

    // ---- P3: compact survivors (superset filter, exact key) ----
    for (int seg = blockIdx.x; seg < NPROB * BPP; seg += GRID) {
        if (tid == 0) sh_lcnt = 0;
        __syncthreads();
        const int p = seg / BPP, cb = seg % BPP;
        const uint32_t pb = pivots[p];
        #pragma unroll
        for (int it = 0; it < 4; ++it) {
            int i = cb * 1024 + it * BLK + tid;
            if (i < NPTS) {
                float sfv = sf[(size_t)p * NPTS + i];   // identical bits to P1
                if ((uint32_t)fast_bin(sfv + FMARG) >= pb) {
                    const int b = p / NCLS, k = p % NCLS;
                    uint32_t kk =
                        score_key(cls[((size_t)b * NPTS + i) * NCLS + k]);
                    unsigned long long entry = ((unsigned long long)kk << 32) |
                                               (uint32_t)(~(uint32_t)i);
                    uint32_t slot = atomicAdd(&sh_lcnt, 1u);  // <=1024
                    sh_key[slot] = entry;
                }
            }
        }
        __syncthreads();
        if (tid == 0 && sh_lcnt)
            sh_lbase = atomicAdd(&cand_cnt[p], sh_lcnt);
        __syncthreads();
        const uint32_t n = sh_lcnt;
        for (uint32_t e = tid; e < n; e += BLK) {
            uint32_t g = sh_lbase + e;
            if (g < CAP) cand[(size_t)p * CAP + g] = sh_key[e];
        }
        __syncthreads();    // sh_key reused next iteration
    }
    grid.sync();

    // ---- P4: per-problem bitonic top-512 + f64 geometry + f32 screen ----
    if (blockIdx.x < NPROB) {
        const int p = blockIdx.x, b = p / NCLS;
        const int cnt = min((int)cand_cnt[p], CAP);
        for (int i = tid; i < CAP; i += BLK)
            sh_key[i] = (i < cnt) ? cand[(size_t)p * CAP + i] : 0ull;
        __syncthreads();
        for (int k2 = 2; k2 <= CAP; k2 <<= 1)
            for (int j = k2 >> 1; j > 0; j >>= 1) {
                for (int i = tid; i < CAP; i += BLK) {
                    int ixj = i ^ j;
                    if (ixj > i) {
                        unsigned long long a = sh_key[i], c = sh_key[ixj];
                        bool up = ((i & k2) == 0);
                        if (up ? (a < c) : (a > c)) {
                            sh_key[i] = c; sh_key[ixj] = a;
                        }
                    }
                }
                __syncthreads();
            }
        for (int t = tid; t < PRE; t += BLK) {
            unsigned long long key = sh_key[t];
            double* D = boxdata + (size_t)(p * PRE + t) * 20;
            float* S = screen + (size_t)(p * PRE + t) * 8;
            if (key == 0ull) {              // defensive: can't happen normally
                cand_idx[p * PRE + t] = 0;
                cand_score[p * PRE + t] = -1.0f;
                #pragma unroll
                for (int m = 0; m < 20; ++m) D[m] = 0.0;
                #pragma unroll
                for (int m = 0; m < 8; ++m) S[m] = 0.0f;
                continue;
            }
            uint32_t idx = ~((uint32_t)key);
            uint32_t ov = (uint32_t)(key >> 32);
            uint32_t ub = (ov & 0x80000000u) ? (ov ^ 0x80000000u) : ~ov;
            float sc = __uint_as_float(ub);
            cand_idx[p * PRE + t] = idx;
            cand_score[p * PRE + t] = sc;

            const float* bp = boxes + ((size_t)b * NPTS + idx) * 7;
            double x = bp[0], y = bp[1], z = bp[2];
            double dx = bp[3], dy = bp[4], dz = bp[5], r = bp[6];
            double c = cos(r), s = sin(r);
            double hx = 0.5 * dx, hy = 0.5 * dy;
            double zlo = z - 0.5 * dz, zhi = z + 0.5 * dz;
            double rad = sqrt(hx * hx + hy * hy);
            D[0] = x; D[1] = y; D[2] = c; D[3] = s; D[4] = hx; D[5] = hy;
            D[6] = zlo; D[7] = zhi; D[8] = dx * dy * dz; D[9] = rad;
            const double lxs[4] = { hx, -hx, -hx,  hx };
            const double lys[4] = { hy,  hy, -hy, -hy };
            #pragma unroll
            for (int m = 0; m < 4; ++m) {
                D[10 + m] = x + lxs[m] * c - lys[m] * s;
                D[14 + m] = y + lxs[m] * s + lys[m] * c;
            }
            S[0] = (float)x; S[1] = (float)y; S[2] = (float)zlo;
            S[3] = (float)zhi; S[4] = (float)rad;
            S[5] = 0.0f; S[6] = 0.0f; S[7] = 0.0f;
        }
    }
    grid.sync();

    // ---- P5: fused f32 screen + wave-parallel exact f64 IoU ----
    {
        const int lane = tid & 63;
        const int wave = blockIdx.x * (BLK / 64) + (tid >> 6);
        const int nwaves = GRID * (BLK / 64);
        for (int W = wave; W < NPROB * WAVES_PER_PROB; W += nwaves) {
            const int prob = W / WAVES_PER_PROB;
            int t = W - prob * WAVES_PER_PROB;
            int cell = t >> 6, r = t & 63;
            int wi = 0;
            while (cell >= 8 - wi) { cell -= 8 - wi; ++wi; }
            const int wj = wi + cell;
            const int bi = wi * 64 + r;
            const int j = wj * 64 + lane;

            bool surv = false;
            {
                const float* SA = screen + (size_t)(prob * PRE + bi) * 8;
                const float* SB = screen + (size_t)(prob * PRE + j) * 8;
                if (j > bi) {
                    float4 a4 = *(const float4*)SA;   // x,y,zlo,zhi
                    float4 b4 = *(const float4*)SB;
                    float hz = fminf(a4.w, b4.w) - fmaxf(a4.z, b4.z);
                    if (hz > 0.0f) {
                        float ddx = a4.x - b4.x, ddy = a4.y - b4.y;
                        float rs = SA[4] + SB[4] + 0.01f;
                        surv = (ddx * ddx + ddy * ddy <= rs * rs);
                    }
                }
            }
            unsigned long long sm = __ballot(surv);
            unsigned long long supw = 0ull;
            const double* A = boxdata + (size_t)(prob * PRE + bi) * 20;

            while (sm) {
                int jb = __ffsll(sm) - 1;
                sm &= sm - 1ull;
                const int bj = wj * 64 + jb;
                const double* B = boxdata + (size_t)(prob * PRE + bj) * 20;

                double PX = 0.0, PY = 0.0;
                bool valid = false;
                if (lane < 8) {
                    const double* S = (lane < 4) ? A : B;
                    const double* O = (lane < 4) ? B : A;
                    int m = lane & 3;
                    PX = S[10 + m]; PY = S[14 + m];
                    double rx = PX - O[0], ry = PY - O[1];
                    double u =  rx * O[2] + ry * O[3];
                    double v = -rx * O[3] + ry * O[2];
                    valid = (fabs(u) <= O[4] + 1e-5) &&
                            (fabs(v) <= O[5] + 1e-5);
                } else if (lane < 24) {
                    int e = lane - 8, m = e >> 2, nn = e & 3;
                    double ax = A[10 + m], ay = A[14 + m];
                    double rax = A[10 + ((m + 1) & 3)] - ax;
                    double ray = A[14 + ((m + 1) & 3)] - ay;
                    double bx = B[10 + nn], by = B[14 + nn];
                    double rbx = B[10 + ((nn + 1) & 3)] - bx;
                    double rby = B[14 + ((nn + 1) & 3)] - by;
                    double d = rax * rby - ray * rbx;
                    if (fabs(d) > 1e-8) {
                        double qx = bx - ax, qy = by - ay;
                        double tt = (qx * rby - qy * rbx) / d;
                        double uu = (qx * ray - qy * rax) / d;
                        valid = (tt >= 0.0 && tt <= 1.0 &&
                                 uu >= 0.0 && uu <= 1.0);
                        PX = ax + tt * rax; PY = ay + tt * ray;
                    }
                }
                if (!valid) { PX = 0.0; PY = 0.0; }

                unsigned long long bal = __ballot(valid);  // lanes 0-23 only
                int cnt = __popcll(bal);
                double sx = PX, sy = PY;
                #pragma unroll
                for (int off = 16; off; off >>= 1) {   // 32-group butterfly
                    sx += __shfl_xor(sx, off);
                    sy += __shfl_xor(sy, off);
                }
                int cdiv = cnt > 0 ? cnt : 1;          // ref: / max(cnt,1)
                double cxc = sx / cdiv, cyc = sy / cdiv;

                double ang = valid ? atan2(PY - cyc, PX - cxc) : 1e9;
                int sidx = lane;

                #pragma unroll
                for (int k = 2; k <= 32; k <<= 1) {
                    #pragma unroll
                    for (int jj = k >> 1; jj > 0; jj >>= 1) {
                        double oang = __shfl_xor(ang, jj);
                        double opx  = __shfl_xor(PX, jj);
                        double opy  = __shfl_xor(PY, jj);
                        int    oidx = __shfl_xor(sidx, jj);
                        bool iLow = (lane & jj) == 0;
                        bool dirUp = (lane & k) == 0;
                        bool mineFirst = (ang < oang) ||
                                         (ang == oang && sidx < oidx);
                        bool keepMine = (mineFirst == (iLow == dirUp));
                        if (!keepMine) {
                            ang = oang; PX = opx; PY = opy; sidx = oidx;
                        }
                    }
                }

                double nxp = __shfl(PX, (lane + 1) & 31);
                double nyp = __shfl(PY, (lane + 1) & 31);
                double fx  = __shfl(PX, 0);
                double fy  = __shfl(PY, 0);
                bool last = (lane == cnt - 1);
                double qx = last ? fx : nxp, qy = last ? fy : nyp;
                double contrib = 0.0;
                if (lane < cnt)
                    contrib = (PX - cxc) * (qy - cyc) -
                              (PY - cyc) * (qx - cxc);
                #pragma unroll
                for (int off = 16; off; off >>= 1)
                    contrib += __shfl_xor(contrib, off);
                double inter = (cnt >= 3) ? 0.5 * fabs(contrib) : 0.0;

                if (lane == 0) {
                    double zt = fmin(A[7], B[7]);
                    double zb = fmax(A[6], B[6]);
                    double hz = zt - zb;
                    bool sup = false;
                    if (hz > 0.0) {
                        double i3 = inter * hz;
                        double den = A[8] + B[8] - i3;
                        if (den < 1e-8) den = 1e-8;
                        sup = (i3 / den) > (double)NMS_TH;
                    }
                    if (sup) supw |= 1ull << jb;
                }
            }

            if (lane == 0)
                mask[(size_t)(prob * PRE + bi) * 8 + wj] = supw;  // exclusive
        }
    }
    grid.sync();

    // ---- P6: greedy NMS scan + padded output ----
    if (blockIdx.x < NPROB) {
        const int p = blockIdx.x;
        const int b = p / NCLS, k = p % NCLS;

        for (int w = tid; w < PRE * 8; w += BLK)
            sh_smask[w] = mask[(size_t)p * PRE * 8 + w];
        for (int i = tid; i < PRE; i += BLK)
            sh_sscore[i] = cand_score[p * PRE + i];
        __syncthreads();

        // Wave-parallel greedy scan; early break at c==POST. Garbage bits in
        // lower-triangle mask words only mark columns j<i (already decided).
        if (tid < 64) {
            const int lane = tid;
            uint32_t supbits = 0;
            int c = 0;
            for (int i = 0; i < PRE; ++i) {
                uint32_t sb = (uint32_t)__shfl((int)supbits, i & 63);
                bool sup_i = (sb >> (i >> 6)) & 1u;
                float sc = sh_sscore[i];
                bool keep = (sc >= SCORE_TH) && !sup_i;
                if (keep) {
                    if (lane == 0) sh_slist[c] = i;
                    ++c;
                    if (c >= POST) break;
                    #pragma unroll
                    for (int w = 0; w < 8; ++w) {
                        unsigned long long m = sh_smask[i * 8 + w];
                        supbits |= (uint32_t)((m >> lane) & 1ull) << w;
                    }
                }
            }
            if (lane == 0) sh_scnt = c;
        }
        __syncthreads();

        const int cnt = sh_scnt;
        for (int t = tid; t < POST; t += BLK) {
            int row = b * (NCLS * POST) + k * POST + t;   // 0..599
            float* ob = out + (size_t)row * 7;
            float* os = out + (size_t)NB * NCLS * POST * 7 + row;
            float* ol = out + (size_t)NB * NCLS * POST * 7 +
                        (size_t)NB * NCLS * POST + row;
            if (t < cnt) {
                int r = sh_slist[t];
                uint32_t idx = cand_idx[p * PRE + r];
                const float* bp = boxes + ((size_t)b * NPTS + idx) * 7;
                #pragma unroll
                for (int c7 = 0; c7 < 7; ++c7) ob[c7] = bp[c7];
                *os = sh_sscore[r];
                *ol = (float)(k + 1);
            } else {
                #pragma unroll
                for (int c7 = 0; c7 < 7; ++c7) ob[c7] = 0.0f;
                *os = 0.0f;
                *ol = 0.0f;
            }
        }
    }
}

extern "C" void kernel_launch(void* const* d_in, const int* in_sizes, int n_in,
                              void* d_out, int out_size, void* d_ws, size_t ws_size,
                              hipStream_t stream)
{
    (void)in_sizes; (void)n_in; (void)out_size; (void)ws_size;
    const float* cls   = (const float*)d_in[0];   // (2,100000,3) f32
    const float* boxes = (const float*)d_in[1];   // (2,100000,7) f32
    float* out = (float*)d_out;
    char* ws = (char*)d_ws;

    void* args[] = { (void*)&cls, (void*)&boxes, (void*)&out, (void*)&ws };
    hipLaunchCooperativeKernel((void*)fused_kernel, dim3(GRID), dim3(BLK),
                               args, 0, stream);
}